// Round 2
// baseline (77.167 us; speedup 1.0000x reference)
//
#include <hip/hip_runtime.h>
#include <hip/hip_bf16.h>
#include <math.h>

// Temporal attention: B=32, N=2048, F=16, T=64
//   y[b,t,f]   = sum_n U1[n] * x[b,n,f,t]
//   r[b,n,u]   = sum_f U3[f] * x[b,n,f,u]
//   z[b,f,u]   = sum_n U2[f,n] * r[b,n,u]
//   product[b,t,u] = sum_f y[b,t,f] * z[b,f,u]
//   E[b,t,u] = sum_s Ve[t,s] * sigmoid(product[b,s,u] + be[s,u])
//   out = softmax over t (axis=1)

#define B_ 32
#define N_ 2048
#define F_ 16
#define T_ 64
#define NPB 64               // n-rows per block in pass 1
#define CHUNKS (N_ / NPB)    // 32 chunks per batch

// ---------------- Pass 1: stream x once (float4), emit partial y/z ---------
__global__ __launch_bounds__(256) void ta_pass1(
    const float* __restrict__ x, const float* __restrict__ U1,
    const float* __restrict__ U2, const float* __restrict__ U3,
    float* __restrict__ partial)
{
  const int blk    = blockIdx.x;
  const int b      = blk / CHUNKS;
  const int chunk  = blk % CHUNKS;
  const int n_base = chunk * NPB;
  const int tid    = threadIdx.x;
  const int tp     = tid & 15;   // t-quad index: covers t = 4*tp .. 4*tp+3
  const int n_sub  = tid >> 4;   // 16 concurrent n per iteration
  const int w      = tid >> 6;
  const int lane   = tid & 63;

  __shared__ float  u1s[NPB];
  __shared__ float  u2t[NPB][F_ + 1];   // [n][f], padded
  __shared__ float4 rlds[NPB][16];      // r[n][u-quad]
  __shared__ float4 red[4][256];        // per-wave y partials [w][f*16+tp]

  if (tid < NPB) u1s[tid] = U1[n_base + tid];
  for (int i = tid; i < NPB * F_; i += 256) {      // coalesced: n fast, f slow
    const int f = i >> 6, n = i & 63;
    u2t[n][f] = U2[f * N_ + n_base + n];
  }
  float u3r[F_];
  #pragma unroll
  for (int f = 0; f < F_; ++f) u3r[f] = U3[f];
  __syncthreads();

  float4 ya[F_];
  #pragma unroll
  for (int f = 0; f < F_; ++f) ya[f] = make_float4(0.f, 0.f, 0.f, 0.f);

  const float* xb = x + ((size_t)b * N_ + n_base) * (F_ * T_);
  #pragma unroll
  for (int it = 0; it < NPB / 16; ++it) {
    const int nl = n_sub + it * 16;
    const float* xn = xb + (size_t)nl * (F_ * T_) + 4 * tp;
    const float u1 = u1s[nl];
    float4 r = make_float4(0.f, 0.f, 0.f, 0.f);
    #pragma unroll
    for (int f = 0; f < F_; ++f) {
      const float4 v = *reinterpret_cast<const float4*>(xn + f * T_);
      ya[f].x = fmaf(u1, v.x, ya[f].x);
      ya[f].y = fmaf(u1, v.y, ya[f].y);
      ya[f].z = fmaf(u1, v.z, ya[f].z);
      ya[f].w = fmaf(u1, v.w, ya[f].w);
      r.x = fmaf(u3r[f], v.x, r.x);
      r.y = fmaf(u3r[f], v.y, r.y);
      r.z = fmaf(u3r[f], v.z, r.z);
      r.w = fmaf(u3r[f], v.w, r.w);
    }
    rlds[nl][tp] = r;
  }

  // reduce ya across the wave's 4 n_sub groups (lane bits 4,5)
  #pragma unroll
  for (int f = 0; f < F_; ++f) {
    ya[f].x += __shfl_xor(ya[f].x, 16);
    ya[f].y += __shfl_xor(ya[f].y, 16);
    ya[f].z += __shfl_xor(ya[f].z, 16);
    ya[f].w += __shfl_xor(ya[f].w, 16);
    ya[f].x += __shfl_xor(ya[f].x, 32);
    ya[f].y += __shfl_xor(ya[f].y, 32);
    ya[f].z += __shfl_xor(ya[f].z, 32);
    ya[f].w += __shfl_xor(ya[f].w, 32);
  }
  if ((lane >> 4) == 0) {
    #pragma unroll
    for (int f = 0; f < F_; ++f) red[w][f * 16 + tp] = ya[f];
  }
  __syncthreads();

  float4* pb = reinterpret_cast<float4*>(partial + (size_t)blk * 2048);
  // y partial: float offset f*64 + t
  {
    const float4 a = red[0][tid], c = red[1][tid], d = red[2][tid], e = red[3][tid];
    float4 yv;
    yv.x = a.x + c.x + d.x + e.x;
    yv.y = a.y + c.y + d.y + e.y;
    yv.z = a.z + c.z + d.z + e.z;
    yv.w = a.w + c.w + d.w + e.w;
    pb[tid] = yv;
  }
  // z partial: z[f][u] = sum_n u2t[n][f] * r[n][u], float offset 1024 + f*64 + u
  {
    const int f = tid >> 4, uq = tid & 15;
    float4 zv = make_float4(0.f, 0.f, 0.f, 0.f);
    #pragma unroll
    for (int n = 0; n < NPB; ++n) {
      const float  u2 = u2t[n][f];
      const float4 r  = rlds[n][uq];
      zv.x = fmaf(u2, r.x, zv.x);
      zv.y = fmaf(u2, r.y, zv.y);
      zv.z = fmaf(u2, r.z, zv.z);
      zv.w = fmaf(u2, r.w, zv.w);
    }
    pb[256 + tid] = zv;
  }
}

// ---------------- Pass 2: reduce partials, product+sigmoid, Ve, softmax ----
__global__ __launch_bounds__(256) void ta_finish(
    const float* __restrict__ partial, const float* __restrict__ be,
    const float* __restrict__ Ve, float* __restrict__ out)
{
  const int b   = blockIdx.x;
  const int tid = threadIdx.x;
  __shared__ float ys[T_][F_ + 1];
  __shared__ float zs[F_][T_];
  __shared__ float sig[T_][T_ + 1];
  __shared__ float Es[T_][T_ + 1];

  // reduce the CHUNKS partials for this batch (float4)
  const float4* p4 = reinterpret_cast<const float4*>(partial) + (size_t)b * CHUNKS * 512;
  #pragma unroll
  for (int k = 0; k < 2; ++k) {
    const int i4 = tid + k * 256;
    float4 s = make_float4(0.f, 0.f, 0.f, 0.f);
    #pragma unroll 4
    for (int j = 0; j < CHUNKS; ++j) {
      const float4 v = p4[(size_t)j * 512 + i4];
      s.x += v.x; s.y += v.y; s.z += v.z; s.w += v.w;
    }
    if (i4 < 256) {
      const int f = i4 >> 4, t0 = (i4 & 15) * 4;
      ys[t0 + 0][f] = s.x; ys[t0 + 1][f] = s.y;
      ys[t0 + 2][f] = s.z; ys[t0 + 3][f] = s.w;
    } else {
      const int j4 = i4 - 256;
      const int f = j4 >> 4, u0 = (j4 & 15) * 4;
      zs[f][u0 + 0] = s.x; zs[f][u0 + 1] = s.y;
      zs[f][u0 + 2] = s.z; zs[f][u0 + 3] = s.w;
    }
  }
  __syncthreads();

  const int tr = tid >> 2;          // row 0..63
  const int ub = (tid & 3) * 16;    // 16-wide u slab
  #pragma unroll
  for (int i = 0; i < 16; ++i) {
    const int u = ub + i;
    float acc = 0.f;
    #pragma unroll
    for (int f = 0; f < F_; ++f) acc = fmaf(ys[tr][f], zs[f][u], acc);
    acc += be[tr * T_ + u];
    sig[tr][u] = 1.f / (1.f + __expf(-acc));
  }
  __syncthreads();
  #pragma unroll
  for (int i = 0; i < 16; ++i) {
    const int u = ub + i;
    float acc = 0.f;
    #pragma unroll
    for (int s = 0; s < T_; ++s) acc = fmaf(Ve[tr * T_ + s], sig[s][u], acc);
    Es[tr][u] = acc;
  }
  __syncthreads();

  // softmax over t (axis=1): 4 threads per column u, 16 rows each
  const int u = tid >> 2, p = tid & 3;
  float m = -INFINITY;
  #pragma unroll
  for (int r = 0; r < 16; ++r) m = fmaxf(m, Es[p * 16 + r][u]);
  m = fmaxf(m, __shfl_xor(m, 1));
  m = fmaxf(m, __shfl_xor(m, 2));
  float den = 0.f;
  #pragma unroll
  for (int r = 0; r < 16; ++r) den += __expf(Es[p * 16 + r][u] - m);
  den += __shfl_xor(den, 1);
  den += __shfl_xor(den, 2);
  const float inv = 1.f / den;
  #pragma unroll
  for (int r = 0; r < 16; ++r)
    out[(size_t)b * T_ * T_ + (p * 16 + r) * T_ + u] =
        __expf(Es[p * 16 + r][u] - m) * inv;
}

extern "C" void kernel_launch(void* const* d_in, const int* in_sizes, int n_in,
                              void* d_out, int out_size, void* d_ws, size_t ws_size,
                              hipStream_t stream) {
  const float* x  = (const float*)d_in[0];
  const float* U1 = (const float*)d_in[1];
  const float* U2 = (const float*)d_in[2];
  const float* U3 = (const float*)d_in[3];
  const float* be = (const float*)d_in[4];
  const float* Ve = (const float*)d_in[5];
  float* out = (float*)d_out;
  float* partial = (float*)d_ws;   // B_*CHUNKS*2048*4 = 8 MB of scratch

  ta_pass1<<<B_ * CHUNKS, 256, 0, stream>>>(x, U1, U2, U3, partial);
  ta_finish<<<B_, 256, 0, stream>>>(partial, be, Ve, out);
}